// Round 6
// baseline (316.656 us; speedup 1.0000x reference)
//
#include <hip/hip_runtime.h>
#include <stdint.h>

#define NHEAD 12
#define DH 64
#define BATCH 4
#define SEQ 2048
#define CDIM 768
#define MROWS (BATCH*SEQ)   // 8192

typedef __attribute__((ext_vector_type(8))) short short8;
typedef __attribute__((ext_vector_type(4))) float floatx4;
typedef unsigned int u32;

__device__ inline unsigned short f2bf(float f) {
    union { float f; unsigned u; } v; v.f = f;
    unsigned r = v.u + 0x7FFFu + ((v.u >> 16) & 1u);
    return (unsigned short)(r >> 16);
}

__device__ __forceinline__ u32 pk_bf16(float a, float b) {
    u32 d;
    asm("v_cvt_pk_bf16_f32 %0, %1, %2" : "=v"(d) : "v"(a), "v"(b));
    return d;
}

__device__ __forceinline__ void async_cp16(const unsigned short* g, unsigned short* l) {
    __builtin_amdgcn_global_load_lds(
        (const __attribute__((address_space(1))) u32*)g,
        (__attribute__((address_space(3))) u32*)l, 16, 0, 0);
}

// ---------------- conversion kernels ----------------
__global__ void convert_f32_bf16(const float* __restrict__ in,
                                 unsigned short* __restrict__ out, int n) {
    int i = (blockIdx.x * blockDim.x + threadIdx.x) * 4;
    if (i + 3 < n) {
        float4 f = *(const float4*)(in + i);
        union { unsigned short s[4]; uint2 u; } p;
        p.s[0] = f2bf(f.x); p.s[1] = f2bf(f.y);
        p.s[2] = f2bf(f.z); p.s[3] = f2bf(f.w);
        *(uint2*)(out + i) = p.u;
    }
}

__global__ __launch_bounds__(256) void transpose_conv(
    const float* __restrict__ in, unsigned short* __restrict__ out,
    int K, int N) {
    __shared__ unsigned short T[64][72];
    const int k0 = blockIdx.x * 64, n0 = blockIdx.y * 64;
    const int t = threadIdx.x;
    const int nc = t & 63, kw = t >> 6;
    for (int i = 0; i < 16; i++) {
        const int kr = kw + i * 4;
        T[nc][kr] = f2bf(in[(size_t)(k0 + kr) * N + n0 + nc]);
    }
    __syncthreads();
    const int row = t >> 2, seg = t & 3;
    uint4 a = *(const uint4*)&T[row][seg * 16];
    uint4 b2 = *(const uint4*)&T[row][seg * 16 + 8];
    unsigned short* o = &out[(size_t)(n0 + row) * K + k0 + seg * 16];
    *(uint4*)o = a;
    *(uint4*)(o + 8) = b2;
}

// ---------------- GEMM: triple-buffered async staging, raw s_barrier ----------------
template<int MODE, int KD>
__global__ __launch_bounds__(256) void gemm_bf16(
    const unsigned short* __restrict__ A,
    const unsigned short* __restrict__ BT,
    const float* __restrict__ bias,
    float* __restrict__ Cout,
    unsigned short* __restrict__ Qout,
    unsigned short* __restrict__ Kout,
    unsigned short* __restrict__ VTout,
    int Ndim)
{
    __shared__ unsigned short As[3][4096];
    __shared__ unsigned short Bs[3][4096];
    const int tid  = threadIdx.x;
    const int wave = tid >> 6;
    const int lane = tid & 63;
    const int l16  = lane & 15;
    const int quad = lane >> 4;
    const int wm = wave >> 1, wn = wave & 1;
    const int m0 = blockIdx.x * 128;
    const int n0 = blockIdx.y * 128;

    const int rloc = lane >> 2;
    const int gs   = (((lane & 3) ^ (rloc & 3) ^ ((rloc >> 2) & 3))) * 8;
    const int ar0  = wave * 32 + rloc;
    const int pg = ((quad ^ (l16 & 3) ^ ((l16 >> 2) & 3))) * 8;

    floatx4 acc[4][4];
    for (int i = 0; i < 4; i++)
        for (int j = 0; j < 4; j++) acc[i][j] = (floatx4)0.0f;

    constexpr int NIT = KD / 32;

    auto stageTo = [&](int s, int buf) {
        const int koff = s * 32;
        for (int ch = 0; ch < 2; ch++) {
            const int row = ar0 + ch * 16;
            async_cp16(&A[(size_t)(m0 + row) * KD + koff + gs],
                       &As[buf][(wave * 2 + ch) * 512]);
            async_cp16(&BT[(size_t)(n0 + row) * KD + koff + gs],
                       &Bs[buf][(wave * 2 + ch) * 512]);
        }
    };
    stageTo(0, 0);
    stageTo(1, 1);

    int buf = 0;
    for (int it = 0; it < NIT; it++) {
        if (it < NIT - 1) asm volatile("s_waitcnt vmcnt(4)" ::: "memory");
        else              asm volatile("s_waitcnt vmcnt(0)" ::: "memory");
        asm volatile("s_barrier" ::: "memory");
        if (it + 2 < NIT) {
            int b2 = buf + 2; if (b2 >= 3) b2 -= 3;
            stageTo(it + 2, b2);
        }
        short8 a[4], b[4];
        for (int i = 0; i < 4; i++)
            a[i] = *(const short8*)&As[buf][(wm * 64 + i * 16 + l16) * 32 + pg];
        for (int j = 0; j < 4; j++)
            b[j] = *(const short8*)&Bs[buf][(wn * 64 + j * 16 + l16) * 32 + pg];
        for (int i = 0; i < 4; i++)
            for (int j = 0; j < 4; j++)
                acc[i][j] = __builtin_amdgcn_mfma_f32_16x16x32_bf16(
                    a[i], b[j], acc[i][j], 0, 0, 0);
        buf++; if (buf >= 3) buf = 0;
    }

    const float QSCALE = 0.18033688011112042f;   // 0.125 * log2(e)
    for (int i = 0; i < 4; i++) {
        const int mbase = m0 + wm * 64 + i * 16 + quad * 4;
        for (int j = 0; j < 4; j++) {
            const int ncj  = n0 + wn * 64 + j * 16;
            const int part = ncj / CDIM;          // uniform per j (16 | 768)
            const int cj   = ncj - part * CDIM;
            const int ncol = ncj + l16;
            const float bv = bias[ncol];
            const int c = cj + l16;
            const int hh = c >> 6, d = c & 63;
            for (int r = 0; r < 4; r++) {
                const int m = mbase + r;
                const float v = acc[i][j][r] + bv;
                if (MODE == 0) {
                    Cout[(size_t)m * Ndim + ncol] = v;
                } else {
                    const int b_ = m >> 11, t = m & 2047;
                    const size_t bh = (size_t)(b_ * NHEAD + hh);
                    if (part == 0)
                        Qout[(bh * SEQ + t) * DH + d] = f2bf(v * QSCALE);
                    else if (part == 1)
                        Kout[(bh * SEQ + t) * DH + d] = f2bf(v);
                    else
                        VTout[(bh * DH + d) * SEQ + t] = f2bf(v);
                }
            }
        }
    }
}

// ---------------- flash attention v6 ----------------
// Waves partition k-tiles (32 keys each) disjointly: kt ≡ wave (mod 4).
// No barriers in the k-loop. K/V frags loaded global->VGPR (L2-resident via
// XCD grouping). P round-trip in wave-private LDS (stride 40: conflict-free).
// Associative merge of accO / L across waves at end of each pass.
__global__ __launch_bounds__(256, 2) void attn_kernel(
    const unsigned short* __restrict__ Q,
    const unsigned short* __restrict__ K,
    const unsigned short* __restrict__ VT,
    unsigned short* __restrict__ O)
{
    __shared__ float MO[4 * 3 * 4 * 256];        // 48KB: [qi][slot][dt][lane*4+r]
    __shared__ float ML[4][4][16];               // 1KB
    __shared__ unsigned short Pl[4][16 * 40];    // 5KB, per-wave

    const int tid  = threadIdx.x;
    const int wave = tid >> 6;
    const int lane = tid & 63;
    const int l16  = lane & 15;
    const int quad = lane >> 4;

    const int lin = blockIdx.x;               // 0..767
    const int grp = lin >> 3;
    const int xs  = grp & 15;
    const int bh  = ((grp >> 4) << 3) | (lin & 7);
    const int h = bh % NHEAD, b = bh / NHEAD;

    const unsigned short* Qp = Q  + (size_t)bh * SEQ * DH;
    const unsigned short* Kp = K  + (size_t)bh * SEQ * DH;
    const unsigned short* Vp = VT + (size_t)bh * DH * SEQ;

    for (int pass = 0; pass < 2; pass++) {
        const int qtile = pass == 0 ? xs : 31 - xs;
        const int qb  = qtile * 64;
        const int nkt = 2 * (qtile + 1);      // 32-key tiles

        short8 aq[4][2];
        for (int qi = 0; qi < 4; qi++)
            for (int c = 0; c < 2; c++)
                aq[qi][c] = *(const short8*)
                    &Qp[(size_t)(qb + qi * 16 + l16) * DH + c * 32 + quad * 8];

        floatx4 accO[4][4];
        for (int qi = 0; qi < 4; qi++)
            for (int dt = 0; dt < 4; dt++) accO[qi][dt] = (floatx4)0.0f;
        float lp[4] = {0.f, 0.f, 0.f, 0.f};

        int kt = pass == 0 ? wave : 3 - wave;   // balance across the pass pair
        short8 bkC[2][2], bkN[2][2], bv[4];
        if (kt < nkt) {
            const int kb = kt * 32;
            for (int jn = 0; jn < 2; jn++)
                for (int c = 0; c < 2; c++)
                    bkC[jn][c] = *(const short8*)
                        &Kp[(size_t)(kb + jn * 16 + l16) * DH + c * 32 + quad * 8];
        }

        for (; kt < nkt; kt += 4) {
            const int kb = kt * 32;
            const bool havN = (kt + 4 < nkt);
            if (havN) {
                const int kbn = kb + 128;
                for (int jn = 0; jn < 2; jn++)
                    for (int c = 0; c < 2; c++)
                        bkN[jn][c] = *(const short8*)
                            &Kp[(size_t)(kbn + jn * 16 + l16) * DH + c * 32 + quad * 8];
            }
            for (int dt = 0; dt < 4; dt++)
                bv[dt] = *(const short8*)
                    &Vp[(size_t)(dt * 16 + l16) * SEQ + kb + quad * 8];

            // ---- phase 1: S^T for all 4 q-subtiles ----
            floatx4 s[4][2];
            for (int qi = 0; qi < 4; qi++)
                for (int jn = 0; jn < 2; jn++) {
                    floatx4 t0 = __builtin_amdgcn_mfma_f32_16x16x32_bf16(
                        bkC[jn][0], aq[qi][0], (floatx4)0.0f, 0, 0, 0);
                    s[qi][jn] = __builtin_amdgcn_mfma_f32_16x16x32_bf16(
                        bkC[jn][1], aq[qi][1], t0, 0, 0, 0);
                }
            if (havN)
                for (int jn = 0; jn < 2; jn++)
                    for (int c = 0; c < 2; c++) bkC[jn][c] = bkN[jn][c];

            // ---- phase 2: softmax + PV per q-subtile ----
            for (int qi = 0; qi < 4; qi++) {
                const int qlo = qb + qi * 16;
                if (kb > qlo + 15) continue;              // fully masked subtile
                if (kb + 31 > qlo) {                      // diagonal: mask
                    const int q = qlo + l16;
                    for (int jn = 0; jn < 2; jn++) {
                        const int key = kb + jn * 16 + quad * 4;
                        for (int r = 0; r < 4; r++)
                            if (key + r > q) s[qi][jn][r] = -1e30f;
                    }
                }
                float sum = lp[qi];
                for (int jn = 0; jn < 2; jn++)
                    for (int r = 0; r < 4; r++) {
                        float p = exp2f(s[qi][jn][r]);
                        s[qi][jn][r] = p;
                        sum += p;
                    }
                lp[qi] = sum;

                for (int jn = 0; jn < 2; jn++) {
                    uint2 u;
                    u.x = pk_bf16(s[qi][jn][0], s[qi][jn][1]);
                    u.y = pk_bf16(s[qi][jn][2], s[qi][jn][3]);
                    *(uint2*)&Pl[wave][l16 * 40 + jn * 16 + quad * 4] = u;
                }
                short8 ap = *(const short8*)&Pl[wave][l16 * 40 + quad * 8];
                for (int dt = 0; dt < 4; dt++)
                    accO[qi][dt] = __builtin_amdgcn_mfma_f32_16x16x32_bf16(
                        ap, bv[dt], accO[qi][dt], 0, 0, 0);
            }
        }

        // ---- cross-wave merge (associative: no rescaling needed) ----
        for (int qi = 0; qi < 4; qi++) {
            if (qi == wave) continue;
            const int slot = (wave > qi) ? wave - 1 : wave;
            for (int dt = 0; dt < 4; dt++)
                *(floatx4*)&MO[(((qi * 3 + slot) * 4 + dt) << 8) + lane * 4] =
                    accO[qi][dt];
        }
        for (int qi = 0; qi < 4; qi++) {
            float Lq = lp[qi];
            Lq += __shfl_xor(Lq, 16);
            Lq += __shfl_xor(Lq, 32);
            if (quad == 0) ML[qi][wave][l16] = Lq;
        }
        __syncthreads();
        {
            const int qi = wave;
            floatx4 o[4];
            for (int dt = 0; dt < 4; dt++) {
                o[dt] = accO[qi][dt];
                for (int slot = 0; slot < 3; slot++)
                    o[dt] += *(const floatx4*)
                        &MO[(((qi * 3 + slot) * 4 + dt) << 8) + lane * 4];
            }
            const float Ls = ML[qi][0][l16] + ML[qi][1][l16] +
                             ML[qi][2][l16] + ML[qi][3][l16];
            for (int r = 0; r < 4; r++) {
                const float Lr = __shfl(Ls, quad * 4 + r, 64);
                const float inv = 1.0f / Lr;
                const int t = qb + wave * 16 + quad * 4 + r;
                const size_t base = ((size_t)b * SEQ + t) * CDIM + h * DH;
                for (int dt = 0; dt < 4; dt++)
                    O[base + dt * 16 + l16] = f2bf(o[dt][r] * inv);
            }
        }
        __syncthreads();   // protect MO/ML before next pass reuses them
    }
}

// ---------------- launch ----------------
extern "C" void kernel_launch(void* const* d_in, const int* in_sizes, int n_in,
                              void* d_out, int out_size, void* d_ws, size_t ws_size,
                              hipStream_t stream) {
    const float* x      = (const float*)d_in[0];
    const float* w_attn = (const float*)d_in[1];
    const float* b_attn = (const float*)d_in[2];
    const float* w_proj = (const float*)d_in[3];
    const float* b_proj = (const float*)d_in[4];
    float* out = (float*)d_out;

    unsigned short* xb   = (unsigned short*)d_ws;
    unsigned short* wta  = xb  + (size_t)MROWS * CDIM;
    unsigned short* wtp  = wta + (size_t)3 * CDIM * CDIM;
    unsigned short* qws  = wtp + (size_t)CDIM * CDIM;
    unsigned short* kws  = qws + (size_t)MROWS * CDIM;
    unsigned short* vtws = kws + (size_t)MROWS * CDIM;
    unsigned short* ob   = xb;

    const int nx = MROWS * CDIM;
    convert_f32_bf16<<<nx / 1024, 256, 0, stream>>>(x, xb, nx);
    transpose_conv<<<dim3(CDIM / 64, 3 * CDIM / 64), 256, 0, stream>>>(
        w_attn, wta, CDIM, 3 * CDIM);
    transpose_conv<<<dim3(CDIM / 64, CDIM / 64), 256, 0, stream>>>(
        w_proj, wtp, CDIM, CDIM);

    dim3 g1(MROWS / 128, (3 * CDIM) / 128);
    gemm_bf16<1, CDIM><<<g1, 256, 0, stream>>>(xb, wta, b_attn, nullptr,
                                               qws, kws, vtws, 3 * CDIM);

    attn_kernel<<<768, 256, 0, stream>>>(qws, kws, vtws, ob);

    dim3 g3(MROWS / 128, CDIM / 128);
    gemm_bf16<0, CDIM><<<g3, 256, 0, stream>>>(ob, wtp, b_proj, out,
                                               nullptr, nullptr, nullptr, CDIM);
}

// Round 7
// 226.152 us; speedup vs baseline: 1.4002x; 1.4002x over previous
//
#include <hip/hip_runtime.h>
#include <stdint.h>

#define NHEAD 12
#define DH 64
#define BATCH 4
#define SEQ 2048
#define CDIM 768
#define MROWS (BATCH*SEQ)   // 8192

typedef __attribute__((ext_vector_type(8))) short short8;
typedef __attribute__((ext_vector_type(4))) float floatx4;
typedef unsigned int u32;

__device__ inline unsigned short f2bf(float f) {
    union { float f; unsigned u; } v; v.f = f;
    unsigned r = v.u + 0x7FFFu + ((v.u >> 16) & 1u);
    return (unsigned short)(r >> 16);
}

__device__ __forceinline__ u32 pk_bf16(float a, float b) {
    u32 d;
    asm("v_cvt_pk_bf16_f32 %0, %1, %2" : "=v"(d) : "v"(a), "v"(b));
    return d;
}

__device__ __forceinline__ void async_cp16(const unsigned short* g, unsigned short* l) {
    __builtin_amdgcn_global_load_lds(
        (const __attribute__((address_space(1))) u32*)g,
        (__attribute__((address_space(3))) u32*)l, 16, 0, 0);
}

// ---------------- conversion kernels ----------------
__global__ void convert_f32_bf16(const float* __restrict__ in,
                                 unsigned short* __restrict__ out, int n) {
    int i = (blockIdx.x * blockDim.x + threadIdx.x) * 4;
    if (i + 3 < n) {
        float4 f = *(const float4*)(in + i);
        union { unsigned short s[4]; uint2 u; } p;
        p.s[0] = f2bf(f.x); p.s[1] = f2bf(f.y);
        p.s[2] = f2bf(f.z); p.s[3] = f2bf(f.w);
        *(uint2*)(out + i) = p.u;
    }
}

__global__ __launch_bounds__(256) void transpose_conv(
    const float* __restrict__ in, unsigned short* __restrict__ out,
    int K, int N) {
    __shared__ unsigned short T[64][72];
    const int k0 = blockIdx.x * 64, n0 = blockIdx.y * 64;
    const int t = threadIdx.x;
    const int nc = t & 63, kw = t >> 6;
    for (int i = 0; i < 16; i++) {
        const int kr = kw + i * 4;
        T[nc][kr] = f2bf(in[(size_t)(k0 + kr) * N + n0 + nc]);
    }
    __syncthreads();
    const int row = t >> 2, seg = t & 3;
    uint4 a = *(const uint4*)&T[row][seg * 16];
    uint4 b2 = *(const uint4*)&T[row][seg * 16 + 8];
    unsigned short* o = &out[(size_t)(n0 + row) * K + k0 + seg * 16];
    *(uint4*)o = a;
    *(uint4*)(o + 8) = b2;
}

// ---------------- GEMM (BMN x BMN tiles, triple-buffered async, raw barrier) ----
template<int MODE, int KD, int BMN>
__global__ __launch_bounds__(256) void gemm_bf16(
    const unsigned short* __restrict__ A,
    const unsigned short* __restrict__ BT,
    const float* __restrict__ bias,
    float* __restrict__ Cout,
    unsigned short* __restrict__ Qout,
    unsigned short* __restrict__ Kout,
    unsigned short* __restrict__ VTout,
    int Ndim)
{
    constexpr int TMN = BMN / 32;     // 16x16 tiles per wave per dim
    constexpr int CH  = BMN / 64;     // 1KB async chunks per wave per side
    __shared__ unsigned short As[3][BMN * 32];
    __shared__ unsigned short Bs[3][BMN * 32];
    const int tid  = threadIdx.x;
    const int wave = tid >> 6;
    const int lane = tid & 63;
    const int l16  = lane & 15;
    const int quad = lane >> 4;
    const int wm = wave >> 1, wn = wave & 1;
    const int m0 = blockIdx.x * BMN;
    const int n0 = blockIdx.y * BMN;

    const int rloc = lane >> 2;
    const int gs   = (((lane & 3) ^ (rloc & 3) ^ ((rloc >> 2) & 3))) * 8;
    const int ar0  = wave * (BMN / 4) + rloc;
    const int pg   = ((quad ^ (l16 & 3) ^ ((l16 >> 2) & 3))) * 8;

    floatx4 acc[TMN][TMN];
    for (int i = 0; i < TMN; i++)
        for (int j = 0; j < TMN; j++) acc[i][j] = (floatx4)0.0f;

    constexpr int NIT = KD / 32;

    auto stageTo = [&](int s, int buf) {
        const int koff = s * 32;
        for (int ch = 0; ch < CH; ch++) {
            const int row = ar0 + ch * 16;
            async_cp16(&A[(size_t)(m0 + row) * KD + koff + gs],
                       &As[buf][(wave * CH + ch) * 512]);
            async_cp16(&BT[(size_t)(n0 + row) * KD + koff + gs],
                       &Bs[buf][(wave * CH + ch) * 512]);
        }
    };
    stageTo(0, 0);
    stageTo(1, 1);

    int buf = 0;
    for (int it = 0; it < NIT; it++) {
        if (it < NIT - 1) {
            if constexpr (BMN == 128)
                asm volatile("s_waitcnt vmcnt(4)" ::: "memory");
            else
                asm volatile("s_waitcnt vmcnt(2)" ::: "memory");
        } else {
            asm volatile("s_waitcnt vmcnt(0)" ::: "memory");
        }
        asm volatile("s_barrier" ::: "memory");
        if (it + 2 < NIT) {
            int b2 = buf + 2; if (b2 >= 3) b2 -= 3;
            stageTo(it + 2, b2);
        }
        short8 a[TMN], b[TMN];
        for (int i = 0; i < TMN; i++)
            a[i] = *(const short8*)&As[buf][(wm * (BMN / 2) + i * 16 + l16) * 32 + pg];
        for (int j = 0; j < TMN; j++)
            b[j] = *(const short8*)&Bs[buf][(wn * (BMN / 2) + j * 16 + l16) * 32 + pg];
        for (int i = 0; i < TMN; i++)
            for (int j = 0; j < TMN; j++)
                acc[i][j] = __builtin_amdgcn_mfma_f32_16x16x32_bf16(
                    a[i], b[j], acc[i][j], 0, 0, 0);
        buf++; if (buf >= 3) buf = 0;
    }

    const float QSCALE = 0.18033688011112042f;   // 0.125 * log2(e)
    for (int i = 0; i < TMN; i++) {
        const int mbase = m0 + wm * (BMN / 2) + i * 16 + quad * 4;
        for (int j = 0; j < TMN; j++) {
            const int ncj  = n0 + wn * (BMN / 2) + j * 16;
            const int part = ncj / CDIM;          // uniform per j (16 | 768)
            const int cj   = ncj - part * CDIM;
            const int ncol = ncj + l16;
            const float bv = bias[ncol];
            const int c = cj + l16;
            const int hh = c >> 6, d = c & 63;
            for (int r = 0; r < 4; r++) {
                const int m = mbase + r;
                const float v = acc[i][j][r] + bv;
                if (MODE == 0) {
                    Cout[(size_t)m * Ndim + ncol] = v;
                } else {
                    const int b_ = m >> 11, t = m & 2047;
                    const size_t bh = (size_t)(b_ * NHEAD + hh);
                    if (part == 0)
                        Qout[(bh * SEQ + t) * DH + d] = f2bf(v * QSCALE);
                    else if (part == 1)
                        Kout[(bh * SEQ + t) * DH + d] = f2bf(v);
                    else
                        VTout[(bh * DH + d) * SEQ + t] = f2bf(v);
                }
            }
        }
    }
}

// ---------------- flash attention v7 (v5 structure + non-draining barrier) ----
__global__ __launch_bounds__(256) void attn_kernel(
    const unsigned short* __restrict__ Q,
    const unsigned short* __restrict__ K,
    const unsigned short* __restrict__ VT,
    unsigned short* __restrict__ O)
{
    __shared__ unsigned short Kl[2][2][64 * 32];
    __shared__ unsigned short Vl[2][2][64 * 32];
    __shared__ unsigned short Pl[4][16 * 68];

    const int tid  = threadIdx.x;
    const int wave = tid >> 6;
    const int lane = tid & 63;
    const int l16  = lane & 15;
    const int quad = lane >> 4;

    const int lin = blockIdx.x;               // 0..767
    const int grp = lin >> 3;
    const int xs  = grp & 15;
    const int bh  = ((grp >> 4) << 3) | (lin & 7);
    const int h = bh % NHEAD, b = bh / NHEAD;

    const unsigned short* Qp = Q  + (size_t)bh * SEQ * DH;
    const unsigned short* Kp = K  + (size_t)bh * SEQ * DH;
    const unsigned short* Vp = VT + (size_t)bh * DH * SEQ;

    const int rloc = lane >> 2;
    const int gofsK = ((lane & 3) ^ (rloc & 3) ^ ((rloc >> 2) & 3)) * 8;
    const int pg = ((quad ^ (l16 & 3) ^ ((l16 >> 2) & 3))) * 8;
    const int krow = wave * 16 + rloc;

    for (int pass = 0; pass < 2; pass++) {
        const int qtile = pass == 0 ? xs : 31 - xs;
        const int qb = qtile * 64;
        const int qw = qb + wave * 16;
        const int nkt = qtile + 1;

        short8 aq[2];
        for (int c = 0; c < 2; c++)
            aq[c] = *(const short8*)&Qp[(size_t)(qw + l16) * DH + c * 32 + quad * 8];

        floatx4 accO[4];
        for (int dt = 0; dt < 4; dt++) accO[dt] = (floatx4)0.0f;
        float lp = 0.0f;

        // stage tile 0 into buf 0
        for (int c = 0; c < 2; c++) {
            async_cp16(&Kp[(size_t)krow * DH + c * 32 + gofsK],
                       &Kl[0][c][wave * 512]);
            async_cp16(&Vp[(size_t)krow * SEQ + 0 + c * 32 + gofsK],
                       &Vl[0][c][wave * 512]);
        }

        for (int kt = 0; kt < nkt; kt++) {
            const int kb  = kt * 64;
            const int cur = kt & 1;

            // tile kt's asyncs (issued a full tile ago) done; then barrier.
            asm volatile("s_waitcnt vmcnt(0)" ::: "memory");
            asm volatile("s_barrier" ::: "memory");

            // prefetch next tile (post-barrier; has whole tile body to land)
            if (kt + 1 < nkt) {
                const int kbn = kb + 64;
                for (int c = 0; c < 2; c++) {
                    async_cp16(&Kp[(size_t)(kbn + krow) * DH + c * 32 + gofsK],
                               &Kl[cur ^ 1][c][wave * 512]);
                    async_cp16(&Vp[(size_t)krow * SEQ + kbn + c * 32 + gofsK],
                               &Vl[cur ^ 1][c][wave * 512]);
                }
            }

            // S^T: lane q = l16, key = kb + jn*16 + quad*4 + r
            floatx4 s[4];
            for (int jn = 0; jn < 4; jn++) {
                s[jn] = (floatx4)0.0f;
                for (int c = 0; c < 2; c++) {
                    short8 bk = *(const short8*)
                        &Kl[cur][c][(jn * 16 + l16) * 32 + pg];
                    s[jn] = __builtin_amdgcn_mfma_f32_16x16x32_bf16(
                        bk, aq[c], s[jn], 0, 0, 0);
                }
            }

            if (kt == nkt - 1) {
                const int q = qw + l16;
                for (int jn = 0; jn < 4; jn++) {
                    const int key = kb + jn * 16 + quad * 4;
                    for (int r = 0; r < 4; r++)
                        if (key + r > q) s[jn][r] = -1e30f;
                }
            }

            for (int jn = 0; jn < 4; jn++)
                for (int r = 0; r < 4; r++) {
                    float p = exp2f(s[jn][r]);
                    s[jn][r] = p;
                    lp += p;
                }

            // P^T -> wave-private LDS (packed cvt + b64), back as A-frags
            for (int jn = 0; jn < 4; jn++) {
                uint2 u;
                u.x = pk_bf16(s[jn][0], s[jn][1]);
                u.y = pk_bf16(s[jn][2], s[jn][3]);
                *(uint2*)&Pl[wave][l16 * 68 + jn * 16 + quad * 4] = u;
            }
            short8 ap[2];
            for (int c = 0; c < 2; c++) {
                union { short8 v; uint2 u2[2]; } a_;
                const int base = l16 * 68 + c * 32 + quad * 8;
                a_.u2[0] = *(const uint2*)&Pl[wave][base];
                a_.u2[1] = *(const uint2*)&Pl[wave][base + 4];
                ap[c] = a_.v;
            }

            for (int dt = 0; dt < 4; dt++)
                for (int c = 0; c < 2; c++) {
                    short8 bv = *(const short8*)
                        &Vl[cur][c][(dt * 16 + l16) * 32 + pg];
                    accO[dt] = __builtin_amdgcn_mfma_f32_16x16x32_bf16(
                        ap[c], bv, accO[dt], 0, 0, 0);
                }
        }

        float L = lp;
        L += __shfl_xor(L, 16);
        L += __shfl_xor(L, 32);
        for (int r = 0; r < 4; r++) {
            const float Lr = __shfl(L, (lane & 48) | (quad * 4 + r), 64);
            const float inv = 1.0f / Lr;
            const int t = qb + wave * 16 + quad * 4 + r;
            const size_t base = ((size_t)b * SEQ + t) * CDIM + h * DH;
            for (int dt = 0; dt < 4; dt++)
                O[base + dt * 16 + l16] = f2bf(accO[dt][r] * inv);
        }
        __syncthreads();   // protect K/V buffers before next pass restages
    }
}

// ---------------- launch ----------------
extern "C" void kernel_launch(void* const* d_in, const int* in_sizes, int n_in,
                              void* d_out, int out_size, void* d_ws, size_t ws_size,
                              hipStream_t stream) {
    const float* x      = (const float*)d_in[0];
    const float* w_attn = (const float*)d_in[1];
    const float* b_attn = (const float*)d_in[2];
    const float* w_proj = (const float*)d_in[3];
    const float* b_proj = (const float*)d_in[4];
    float* out = (float*)d_out;

    unsigned short* xb   = (unsigned short*)d_ws;
    unsigned short* wta  = xb  + (size_t)MROWS * CDIM;
    unsigned short* wtp  = wta + (size_t)3 * CDIM * CDIM;
    unsigned short* qws  = wtp + (size_t)CDIM * CDIM;
    unsigned short* kws  = qws + (size_t)MROWS * CDIM;
    unsigned short* vtws = kws + (size_t)MROWS * CDIM;
    unsigned short* ob   = xb;

    const int nx = MROWS * CDIM;
    convert_f32_bf16<<<nx / 1024, 256, 0, stream>>>(x, xb, nx);
    transpose_conv<<<dim3(CDIM / 64, 3 * CDIM / 64), 256, 0, stream>>>(
        w_attn, wta, CDIM, 3 * CDIM);
    transpose_conv<<<dim3(CDIM / 64, CDIM / 64), 256, 0, stream>>>(
        w_proj, wtp, CDIM, CDIM);

    dim3 g1(MROWS / 128, (3 * CDIM) / 128);
    gemm_bf16<1, CDIM, 128><<<g1, 256, 0, stream>>>(xb, wta, b_attn, nullptr,
                                                    qws, kws, vtws, 3 * CDIM);

    attn_kernel<<<768, 256, 0, stream>>>(qws, kws, vtws, ob);

    dim3 g3(MROWS / 64, CDIM / 64);
    gemm_bf16<0, CDIM, 64><<<g3, 256, 0, stream>>>(ob, wtp, b_proj, out,
                                                   nullptr, nullptr, nullptr, CDIM);
}

// Round 8
// 210.833 us; speedup vs baseline: 1.5019x; 1.0727x over previous
//
#include <hip/hip_runtime.h>
#include <stdint.h>

#define NHEAD 12
#define DH 64
#define BATCH 4
#define SEQ 2048
#define CDIM 768
#define MROWS (BATCH*SEQ)   // 8192

typedef __attribute__((ext_vector_type(8))) short short8;
typedef __attribute__((ext_vector_type(4))) float floatx4;
typedef unsigned int u32;

__device__ inline unsigned short f2bf(float f) {
    union { float f; unsigned u; } v; v.f = f;
    unsigned r = v.u + 0x7FFFu + ((v.u >> 16) & 1u);
    return (unsigned short)(r >> 16);
}

__device__ __forceinline__ u32 pk_bf16(float a, float b) {
    u32 d;
    asm("v_cvt_pk_bf16_f32 %0, %1, %2" : "=v"(d) : "v"(a), "v"(b));
    return d;
}

__device__ __forceinline__ void async_cp16(const unsigned short* g, unsigned short* l) {
    __builtin_amdgcn_global_load_lds(
        (const __attribute__((address_space(1))) u32*)g,
        (__attribute__((address_space(3))) u32*)l, 16, 0, 0);
}

template<int N> __device__ __forceinline__ void waitcnt_vm() {
    if constexpr (N == 0)      asm volatile("s_waitcnt vmcnt(0)" ::: "memory");
    else if constexpr (N == 3) asm volatile("s_waitcnt vmcnt(3)" ::: "memory");
    else if constexpr (N == 4) asm volatile("s_waitcnt vmcnt(4)" ::: "memory");
}

// ---------------- fused prep: x->bf16, w_attn^T->bf16, w_proj^T->bf16 -------
__device__ __forceinline__ void transpose_tile(
    const float* __restrict__ in, unsigned short* __restrict__ out,
    int K, int N, int k0, int n0, unsigned short (*T)[72]) {
    const int t = threadIdx.x;
    const int nc = t & 63, kw = t >> 6;
    for (int i = 0; i < 16; i++) {
        const int kr = kw + i * 4;
        T[nc][kr] = f2bf(in[(size_t)(k0 + kr) * N + n0 + nc]);
    }
    __syncthreads();
    const int row = t >> 2, seg = t & 3;
    uint4 a = *(const uint4*)&T[row][seg * 16];
    uint4 b2 = *(const uint4*)&T[row][seg * 16 + 8];
    unsigned short* o = &out[(size_t)(n0 + row) * K + k0 + seg * 16];
    *(uint4*)o = a;
    *(uint4*)(o + 8) = b2;
}

__global__ __launch_bounds__(256) void prep_kernel(
    const float* __restrict__ x,      unsigned short* __restrict__ xb,
    const float* __restrict__ wa,     unsigned short* __restrict__ wta,
    const float* __restrict__ wp,     unsigned short* __restrict__ wtp) {
    __shared__ unsigned short T[64][72];
    const int lin = blockIdx.x;
    if (lin < 6144) {                      // convert x: 1024 elems/block
        const int i = (lin * 256 + threadIdx.x) * 4;
        float4 f = *(const float4*)(x + i);
        union { unsigned short s[4]; uint2 u; } p;
        p.s[0] = f2bf(f.x); p.s[1] = f2bf(f.y);
        p.s[2] = f2bf(f.z); p.s[3] = f2bf(f.w);
        *(uint2*)(xb + i) = p.u;
    } else if (lin < 6144 + 432) {         // w_attn^T (768 x 2304)
        const int t2 = lin - 6144;
        transpose_tile(wa, wta, CDIM, 3 * CDIM, (t2 % 12) * 64, (t2 / 12) * 64, T);
    } else {                               // w_proj^T (768 x 768)
        const int t3 = lin - 6576;
        transpose_tile(wp, wtp, CDIM, CDIM, (t3 % 12) * 64, (t3 / 12) * 64, T);
    }
}

// ---------------- GEMM (BM x BN tiles, triple-buffered async, raw barrier) ----
// MODE 0: fp32 C. MODE 1: QKV epilogue; V-part blocks transpose via LDS.
template<int MODE, int KD, int BM, int BN>
__global__ __launch_bounds__(256) void gemm_bf16(
    const unsigned short* __restrict__ A,
    const unsigned short* __restrict__ BT,
    const float* __restrict__ bias,
    float* __restrict__ Cout,
    unsigned short* __restrict__ Qout,
    unsigned short* __restrict__ Kout,
    unsigned short* __restrict__ VTout,
    int Ndim)
{
    constexpr int TM = BM / 32, TN = BN / 32;
    constexpr int CHA = BM / 64, CHB = BN / 64;
    __shared__ unsigned short SH[3 * (BM + BN) * 32];
    auto As = [&](int b3) { return &SH[b3 * BM * 32]; };
    auto Bs = [&](int b3) { return &SH[3 * BM * 32 + b3 * BN * 32]; };

    const int tid  = threadIdx.x;
    const int wave = tid >> 6;
    const int lane = tid & 63;
    const int l16  = lane & 15;
    const int quad = lane >> 4;
    const int wm = wave >> 1, wn = wave & 1;
    const int m0 = blockIdx.x * BM;
    const int n0 = blockIdx.y * BN;

    const int rloc = lane >> 2;
    const int gs   = (((lane & 3) ^ (rloc & 3) ^ ((rloc >> 2) & 3))) * 8;
    const int pg   = ((quad ^ (l16 & 3) ^ ((l16 >> 2) & 3))) * 8;

    floatx4 acc[TM][TN];
    for (int i = 0; i < TM; i++)
        for (int j = 0; j < TN; j++) acc[i][j] = (floatx4)0.0f;

    constexpr int NIT = KD / 32;

    auto stageTo = [&](int s, int buf) {
        const int koff = s * 32;
        for (int ch = 0; ch < CHA; ch++) {
            const int row = wave * CHA * 16 + ch * 16 + rloc;
            async_cp16(&A[(size_t)(m0 + row) * KD + koff + gs],
                       &As(buf)[(wave * CHA + ch) * 512]);
        }
        for (int ch = 0; ch < CHB; ch++) {
            const int row = wave * CHB * 16 + ch * 16 + rloc;
            async_cp16(&BT[(size_t)(n0 + row) * KD + koff + gs],
                       &Bs(buf)[(wave * CHB + ch) * 512]);
        }
    };
    stageTo(0, 0);
    stageTo(1, 1);

    int buf = 0;
    for (int it = 0; it < NIT; it++) {
        if (it < NIT - 1) waitcnt_vm<CHA + CHB>();
        else              waitcnt_vm<0>();
        asm volatile("s_barrier" ::: "memory");
        if (it + 2 < NIT) {
            int b2 = buf + 2; if (b2 >= 3) b2 -= 3;
            stageTo(it + 2, b2);
        }
        short8 a[TM], b[TN];
        for (int i = 0; i < TM; i++)
            a[i] = *(const short8*)&As(buf)[(wm * (BM / 2) + i * 16 + l16) * 32 + pg];
        for (int j = 0; j < TN; j++)
            b[j] = *(const short8*)&Bs(buf)[(wn * (BN / 2) + j * 16 + l16) * 32 + pg];
        for (int i = 0; i < TM; i++)
            for (int j = 0; j < TN; j++)
                acc[i][j] = __builtin_amdgcn_mfma_f32_16x16x32_bf16(
                    a[i], b[j], acc[i][j], 0, 0, 0);
        buf++; if (buf >= 3) buf = 0;
    }

    const float QSCALE = 0.18033688011112042f;   // 0.125 * log2(e)

    if (MODE == 1 && (n0 / CDIM) == 2) {
        // ---- V blocks: transpose 64x64 wave tile via LDS, coalesced VT ----
        __syncthreads();                           // done reading SH
        unsigned short* scr = &SH[wave * (64 * 68)];
        for (int i = 0; i < TM; i++) {
            const int tl = i * 16 + quad * 4;
            for (int j = 0; j < TN; j++) {
                const int dl = j * 16 + l16;
                const float bv = bias[n0 + wn * 64 + j * 16 + l16];
                uint2 u;
                u.x = pk_bf16(acc[i][j][0] + bv, acc[i][j][1] + bv);
                u.y = pk_bf16(acc[i][j][2] + bv, acc[i][j][3] + bv);
                *(uint2*)&scr[dl * 68 + tl] = u;
            }
        }
        const int b_ = m0 >> 11;
        const int tg = (m0 & 2047) + wm * 64;
        const int h  = (n0 - 2 * CDIM + wn * 64) >> 6;
        const size_t rowbase = ((size_t)(b_ * NHEAD + h)) * DH;
        for (int p = 0; p < 8; p++) {
            const int d  = p * 8 + (lane >> 3);
            const int tc = (lane & 7) * 8;
            uint4 v = *(const uint4*)&scr[d * 68 + tc];
            *(uint4*)&VTout[(rowbase + d) * SEQ + tg + tc] = v;
        }
        return;
    }

    for (int i = 0; i < TM; i++) {
        const int mbase = m0 + wm * (BM / 2) + i * 16 + quad * 4;
        for (int j = 0; j < TN; j++) {
            const int ncj  = n0 + wn * (BN / 2) + j * 16;
            const int ncol = ncj + l16;
            const float bv = bias[ncol];
            for (int r = 0; r < 4; r++) {
                const int m = mbase + r;
                const float v = acc[i][j][r] + bv;
                if (MODE == 0) {
                    Cout[(size_t)m * Ndim + ncol] = v;
                } else {
                    const int part = ncj / CDIM;   // 0 or 1 here
                    const int c = ncol - part * CDIM;
                    const int hh = c >> 6, d = c & 63;
                    const int b_ = m >> 11, t = m & 2047;
                    const size_t bh = (size_t)(b_ * NHEAD + hh);
                    if (part == 0)
                        Qout[(bh * SEQ + t) * DH + d] = f2bf(v * QSCALE);
                    else
                        Kout[(bh * SEQ + t) * DH + d] = f2bf(v);
                }
            }
        }
    }
}

// ---------------- flash attention v7 (kept from R6) ----------------
__global__ __launch_bounds__(256) void attn_kernel(
    const unsigned short* __restrict__ Q,
    const unsigned short* __restrict__ K,
    const unsigned short* __restrict__ VT,
    unsigned short* __restrict__ O)
{
    __shared__ unsigned short Kl[2][2][64 * 32];
    __shared__ unsigned short Vl[2][2][64 * 32];
    __shared__ unsigned short Pl[4][16 * 68];

    const int tid  = threadIdx.x;
    const int wave = tid >> 6;
    const int lane = tid & 63;
    const int l16  = lane & 15;
    const int quad = lane >> 4;

    const int lin = blockIdx.x;               // 0..767
    const int grp = lin >> 3;
    const int xs  = grp & 15;
    const int bh  = ((grp >> 4) << 3) | (lin & 7);
    const int h = bh % NHEAD, b = bh / NHEAD;

    const unsigned short* Qp = Q  + (size_t)bh * SEQ * DH;
    const unsigned short* Kp = K  + (size_t)bh * SEQ * DH;
    const unsigned short* Vp = VT + (size_t)bh * DH * SEQ;

    const int rloc = lane >> 2;
    const int gofsK = ((lane & 3) ^ (rloc & 3) ^ ((rloc >> 2) & 3)) * 8;
    const int pg = ((quad ^ (l16 & 3) ^ ((l16 >> 2) & 3))) * 8;
    const int krow = wave * 16 + rloc;

    for (int pass = 0; pass < 2; pass++) {
        const int qtile = pass == 0 ? xs : 31 - xs;
        const int qb = qtile * 64;
        const int qw = qb + wave * 16;
        const int nkt = qtile + 1;

        short8 aq[2];
        for (int c = 0; c < 2; c++)
            aq[c] = *(const short8*)&Qp[(size_t)(qw + l16) * DH + c * 32 + quad * 8];

        floatx4 accO[4];
        for (int dt = 0; dt < 4; dt++) accO[dt] = (floatx4)0.0f;
        float lp = 0.0f;

        for (int c = 0; c < 2; c++) {
            async_cp16(&Kp[(size_t)krow * DH + c * 32 + gofsK],
                       &Kl[0][c][wave * 512]);
            async_cp16(&Vp[(size_t)krow * SEQ + 0 + c * 32 + gofsK],
                       &Vl[0][c][wave * 512]);
        }

        for (int kt = 0; kt < nkt; kt++) {
            const int kb  = kt * 64;
            const int cur = kt & 1;

            asm volatile("s_waitcnt vmcnt(0)" ::: "memory");
            asm volatile("s_barrier" ::: "memory");

            if (kt + 1 < nkt) {
                const int kbn = kb + 64;
                for (int c = 0; c < 2; c++) {
                    async_cp16(&Kp[(size_t)(kbn + krow) * DH + c * 32 + gofsK],
                               &Kl[cur ^ 1][c][wave * 512]);
                    async_cp16(&Vp[(size_t)krow * SEQ + kbn + c * 32 + gofsK],
                               &Vl[cur ^ 1][c][wave * 512]);
                }
            }

            floatx4 s[4];
            for (int jn = 0; jn < 4; jn++) {
                s[jn] = (floatx4)0.0f;
                for (int c = 0; c < 2; c++) {
                    short8 bk = *(const short8*)
                        &Kl[cur][c][(jn * 16 + l16) * 32 + pg];
                    s[jn] = __builtin_amdgcn_mfma_f32_16x16x32_bf16(
                        bk, aq[c], s[jn], 0, 0, 0);
                }
            }

            if (kt == nkt - 1) {
                const int q = qw + l16;
                for (int jn = 0; jn < 4; jn++) {
                    const int key = kb + jn * 16 + quad * 4;
                    for (int r = 0; r < 4; r++)
                        if (key + r > q) s[jn][r] = -1e30f;
                }
            }

            for (int jn = 0; jn < 4; jn++)
                for (int r = 0; r < 4; r++) {
                    float p = exp2f(s[jn][r]);
                    s[jn][r] = p;
                    lp += p;
                }

            for (int jn = 0; jn < 4; jn++) {
                uint2 u;
                u.x = pk_bf16(s[jn][0], s[jn][1]);
                u.y = pk_bf16(s[jn][2], s[jn][3]);
                *(uint2*)&Pl[wave][l16 * 68 + jn * 16 + quad * 4] = u;
            }
            short8 ap[2];
            for (int c = 0; c < 2; c++) {
                union { short8 v; uint2 u2[2]; } a_;
                const int base = l16 * 68 + c * 32 + quad * 8;
                a_.u2[0] = *(const uint2*)&Pl[wave][base];
                a_.u2[1] = *(const uint2*)&Pl[wave][base + 4];
                ap[c] = a_.v;
            }

            for (int dt = 0; dt < 4; dt++)
                for (int c = 0; c < 2; c++) {
                    short8 bv = *(const short8*)
                        &Vl[cur][c][(dt * 16 + l16) * 32 + pg];
                    accO[dt] = __builtin_amdgcn_mfma_f32_16x16x32_bf16(
                        ap[c], bv, accO[dt], 0, 0, 0);
                }
        }

        float L = lp;
        L += __shfl_xor(L, 16);
        L += __shfl_xor(L, 32);
        for (int r = 0; r < 4; r++) {
            const float Lr = __shfl(L, (lane & 48) | (quad * 4 + r), 64);
            const float inv = 1.0f / Lr;
            const int t = qb + wave * 16 + quad * 4 + r;
            const size_t base = ((size_t)b * SEQ + t) * CDIM + h * DH;
            for (int dt = 0; dt < 4; dt++)
                O[base + dt * 16 + l16] = f2bf(accO[dt][r] * inv);
        }
        __syncthreads();
    }
}

// ---------------- launch ----------------
extern "C" void kernel_launch(void* const* d_in, const int* in_sizes, int n_in,
                              void* d_out, int out_size, void* d_ws, size_t ws_size,
                              hipStream_t stream) {
    const float* x      = (const float*)d_in[0];
    const float* w_attn = (const float*)d_in[1];
    const float* b_attn = (const float*)d_in[2];
    const float* w_proj = (const float*)d_in[3];
    const float* b_proj = (const float*)d_in[4];
    float* out = (float*)d_out;

    unsigned short* xb   = (unsigned short*)d_ws;
    unsigned short* wta  = xb  + (size_t)MROWS * CDIM;
    unsigned short* wtp  = wta + (size_t)3 * CDIM * CDIM;
    unsigned short* qws  = wtp + (size_t)CDIM * CDIM;
    unsigned short* kws  = qws + (size_t)MROWS * CDIM;
    unsigned short* vtws = kws + (size_t)MROWS * CDIM;
    unsigned short* ob   = xb;

    prep_kernel<<<6720, 256, 0, stream>>>(x, xb, w_attn, wta, w_proj, wtp);

    dim3 g1(MROWS / 128, (3 * CDIM) / 128);
    gemm_bf16<1, CDIM, 128, 128><<<g1, 256, 0, stream>>>(
        xb, wta, b_attn, nullptr, qws, kws, vtws, 3 * CDIM);

    attn_kernel<<<768, 256, 0, stream>>>(qws, kws, vtws, ob);

    dim3 g3(MROWS / 64, CDIM / 128);
    gemm_bf16<0, CDIM, 64, 128><<<g3, 256, 0, stream>>>(
        ob, wtp, b_proj, out, nullptr, nullptr, nullptr, CDIM);
}